// Round 4
// baseline (668.376 us; speedup 1.0000x reference)
//
#include <hip/hip_runtime.h>
#include <hip/hip_bf16.h>

// SMoE: B=4 S=2048 D=1024 F=2048 E=8 K=2
#define DD 1024
#define FF 2048
#define EE 8
#define NT 8192            // B*S tokens
#define NRCAP 18432        // 72 tiles of 256 rows (16384 + 8*255 max pad)
#define MAXT256 72
#define MAXT128 144

typedef __attribute__((ext_vector_type(8))) short bf16x8;
typedef __attribute__((ext_vector_type(4))) float f32x4;

__device__ __forceinline__ ushort f2bf(float f) {
  __hip_bfloat16 h = __float2bfloat16(f);
  return *reinterpret_cast<ushort*>(&h);
}

__device__ __forceinline__ void gload16(const void* g, void* l) {
  __builtin_amdgcn_global_load_lds((const __attribute__((address_space(1))) void*)g,
                                   (__attribute__((address_space(3))) void*)l, 16, 0, 0);
}

// legacy 4-slot swizzle (BK=32 kernels: ffn2)
__device__ __forceinline__ int swz_of_row(int r) { return ((r >> 1) & 3) << 4; }

// ---------------- 64x64 vectorized transpose+cast: f32 [E][R][C] -> bf16 [E][C][R]
__global__ __launch_bounds__(256) void k_transpose64(const float* __restrict__ in,
                                                     ushort* __restrict__ outT, int R, int C) {
  __shared__ ushort tile[64][68];
  const int e = blockIdx.z;
  const int c0 = blockIdx.x * 64, r0 = blockIdx.y * 64;
  const float* ip = in + (size_t)e * R * C;
  const int cq = threadIdx.x & 15, rr = threadIdx.x >> 4;
  #pragma unroll
  for (int p = 0; p < 4; p++) {
    const int r = rr + 16 * p;
    float4 v = *reinterpret_cast<const float4*>(ip + (size_t)(r0 + r) * C + c0 + 4 * cq);
    ushort4 u = make_ushort4(f2bf(v.x), f2bf(v.y), f2bf(v.z), f2bf(v.w));
    *reinterpret_cast<ushort4*>(&tile[r][4 * cq]) = u;
  }
  __syncthreads();
  ushort* op = outT + (size_t)e * C * R;
  const int rq = threadIdx.x & 15, cc = threadIdx.x >> 4;
  #pragma unroll
  for (int p = 0; p < 4; p++) {
    const int c = cc + 16 * p;
    ushort4 u = make_ushort4(tile[4 * rq + 0][c], tile[4 * rq + 1][c],
                             tile[4 * rq + 2][c], tile[4 * rq + 3][c]);
    *reinterpret_cast<ushort4*>(op + (size_t)(c0 + c) * R + r0 + 4 * rq) = u;
  }
}

// ---------------- interleaving 64x64 transpose for W1a/W1b -> BT1 [E][4096][D]
__global__ __launch_bounds__(256) void k_transpose_pair64(const float* __restrict__ in,
                                                          ushort* __restrict__ outT, int half) {
  __shared__ ushort tile[64][68];
  const int e = blockIdx.z;
  const int f0 = blockIdx.x * 64, d0 = blockIdx.y * 64;
  const float* ip = in + (size_t)e * DD * FF;
  const int cq = threadIdx.x & 15, rr = threadIdx.x >> 4;
  #pragma unroll
  for (int p = 0; p < 4; p++) {
    const int r = rr + 16 * p;
    float4 v = *reinterpret_cast<const float4*>(ip + (size_t)(d0 + r) * FF + f0 + 4 * cq);
    ushort4 u = make_ushort4(f2bf(v.x), f2bf(v.y), f2bf(v.z), f2bf(v.w));
    *reinterpret_cast<ushort4*>(&tile[r][4 * cq]) = u;
  }
  __syncthreads();
  ushort* op = outT + (size_t)e * 4096 * DD;
  const int rq = threadIdx.x & 15, cc = threadIdx.x >> 4;
  #pragma unroll
  for (int p = 0; p < 4; p++) {
    const int f = f0 + cc + 16 * p;
    const int rmap = ((f >> 4) << 5) + half * 16 + (f & 15);
    ushort4 u = make_ushort4(tile[4 * rq + 0][cc + 16 * p], tile[4 * rq + 1][cc + 16 * p],
                             tile[4 * rq + 2][cc + 16 * p], tile[4 * rq + 3][cc + 16 * p]);
    *reinterpret_cast<ushort4*>(op + (size_t)rmap * DD + d0 + 4 * rq) = u;
  }
}

// ---------------- RMSNorm + gating (one block per token) ----------------
__global__ __launch_bounds__(256) void k_rms_gate(
    const float* __restrict__ x, const float* __restrict__ rms_w,
    const float* __restrict__ Wg, const float* __restrict__ bg,
    ushort* __restrict__ xn, float* __restrict__ outW,
    int* __restrict__ tk_e, float* __restrict__ tk_w, int* __restrict__ counts) {
  const int t = blockIdx.x, tid = threadIdx.x;
  const int wid = tid >> 6, lane = tid & 63;
  const float4 xv = reinterpret_cast<const float4*>(x + (size_t)t * DD)[tid];
  float ss = xv.x * xv.x + xv.y * xv.y + xv.z * xv.z + xv.w * xv.w;
  #pragma unroll
  for (int m = 32; m; m >>= 1) ss += __shfl_xor(ss, m);
  __shared__ float sred[4];
  __shared__ float slog[4][8];
  if (lane == 0) sred[wid] = ss;
  __syncthreads();
  const float ms = (sred[0] + sred[1] + sred[2] + sred[3]) * (1.0f / (float)DD);
  const float sc = 1.0f / sqrtf(ms + 1.1920929e-07f);   // finfo(f32).eps
  const float4 wv = reinterpret_cast<const float4*>(rms_w)[tid];
  float xs[4] = { xv.x * sc * wv.x, xv.y * sc * wv.y, xv.z * sc * wv.z, xv.w * sc * wv.w };
  ushort4 st = make_ushort4(f2bf(xs[0]), f2bf(xs[1]), f2bf(xs[2]), f2bf(xs[3]));
  reinterpret_cast<ushort4*>(xn + (size_t)t * DD)[tid] = st;
  float lg[8] = {0.f, 0.f, 0.f, 0.f, 0.f, 0.f, 0.f, 0.f};
  const float4* Wg4 = reinterpret_cast<const float4*>(Wg);
  const int d = tid * 4;
  #pragma unroll
  for (int j = 0; j < 4; j++) {
    float4 wa = Wg4[(d + j) * 2];
    float4 wb = Wg4[(d + j) * 2 + 1];
    lg[0] += xs[j] * wa.x; lg[1] += xs[j] * wa.y; lg[2] += xs[j] * wa.z; lg[3] += xs[j] * wa.w;
    lg[4] += xs[j] * wb.x; lg[5] += xs[j] * wb.y; lg[6] += xs[j] * wb.z; lg[7] += xs[j] * wb.w;
  }
  #pragma unroll
  for (int m = 32; m; m >>= 1) {
    #pragma unroll
    for (int i = 0; i < 8; i++) lg[i] += __shfl_xor(lg[i], m);
  }
  if (lane == 0) {
    #pragma unroll
    for (int i = 0; i < 8; i++) slog[wid][i] = lg[i];
  }
  __syncthreads();
  if (tid == 0) {
    float l[8];
    for (int i = 0; i < 8; i++)
      l[i] = slog[0][i] + slog[1][i] + slog[2][i] + slog[3][i] + bg[i];
    int i0 = 0; float v0 = l[0];
    for (int i = 1; i < 8; i++) if (l[i] > v0) { v0 = l[i]; i0 = i; }   // first max (jax tie rule)
    int i1 = -1; float v1 = -3.4e38f;
    for (int i = 0; i < 8; i++) if (i != i0 && l[i] > v1) { v1 = l[i]; i1 = i; }
    const float e1v = __expf(v1 - v0);
    const float w0 = 1.0f / (1.0f + e1v);
    const float w1 = e1v * w0;
    float* wrow = outW + (size_t)t * EE;
    for (int i = 0; i < 8; i++) wrow[i] = 0.f;
    wrow[i0] = w0; wrow[i1] = w1;
    tk_e[t] = i0 | (i1 << 8);
    tk_w[2 * t] = w0; tk_w[2 * t + 1] = w1;
    atomicAdd(&counts[i0], 1);
    atomicAdd(&counts[i1], 1);
  }
}

// ---------------- scan counts -> 256-aligned bases; init row map ----------------
__global__ void k_scan(const int* __restrict__ counts, int* __restrict__ base,
                       int* __restrict__ cursors, int* __restrict__ tok_of_row) {
  if (threadIdx.x == 0) {
    int acc = 0;
    for (int e = 0; e < EE; e++) {
      base[e] = acc;
      cursors[e] = 0;
      acc += ((counts[e] + 255) >> 8) << 8;
    }
    base[EE] = acc;
  }
  for (int i = threadIdx.x; i < NRCAP; i += 256) tok_of_row[i] = -1;
}

// ---------------- scatter tokens into expert-grouped rows ----------------
__global__ __launch_bounds__(256) void k_scatter(
    const int* __restrict__ tk_e, const int* __restrict__ base, int* __restrict__ cursors,
    int* __restrict__ tok_of_row, int* __restrict__ rows_of_tok) {
  const int t = blockIdx.x * 256 + threadIdx.x;
  if (t >= NT) return;
  const int ee = tk_e[t];
  const int e0 = ee & 255, e1 = (ee >> 8) & 255;
  int s = atomicAdd(&cursors[e0], 1);
  int row = base[e0] + s;
  tok_of_row[row] = t; rows_of_tok[2 * t] = row;
  s = atomicAdd(&cursors[e1], 1);
  row = base[e1] + s;
  tok_of_row[row] = t; rows_of_tok[2 * t + 1] = row;
}

// ---------------- grouped GEMM1: 256x256 tile, BK=64, 8 waves, deep pipeline ----------------
// dbuf LDS (128 KiB), counted vmcnt(8) (tile T+1's loads stay in flight across barriers),
// 4 sub-phases per K-tile (one C-quadrant: 12 ds_read_b128 + 16 MFMA each).
// LDS layout: [row][slot] with slot = chunk ^ (row&7), chunk = 16B column group.
__global__ __launch_bounds__(512, 2) void k_ffn1(
    const ushort* __restrict__ xn, const ushort* __restrict__ BT1,
    const float* __restrict__ b1a, const float* __restrict__ b1b,
    const int* __restrict__ tok_of_row, const int* __restrict__ base,
    ushort* __restrict__ H) {
  const int row0 = blockIdx.y * 256;
  if (row0 >= base[EE]) return;
  int e = 0;
  while (e < EE - 1 && row0 >= base[e + 1]) e++;
  const int c0 = blockIdx.x * 256;            // interleaved column base
  const int tid = threadIdx.x;                // 0..511
  const int wid = tid >> 6, lane = tid & 63;
  const int wr = wid >> 2, wcn = wid & 3;     // 2 M-waves x 4 N-waves; wave out = 128x64
  __shared__ ushort sA[2][256 * 64];          // 2 x 32 KiB
  __shared__ ushort sB[2][256 * 64];          // 2 x 32 KiB

  // ---- staging map: issue g covers tile rows g*64..g*64+63; thread -> (row, slot)
  const int rS = tid >> 3;                    // 0..63
  const int slot = tid & 7;
  const ushort* gAp[4];
  const ushort* gBp[4];
  #pragma unroll
  for (int g = 0; g < 4; g++) {
    const int R = g * 64 + rS;
    int tok = tok_of_row[row0 + R]; if (tok < 0) tok = 0;
    const int c = slot ^ (R & 7);             // pre-swizzled global chunk
    gAp[g] = xn + (size_t)tok * DD + c * 8;
    gBp[g] = BT1 + ((size_t)e * 4096 + c0 + R) * DD + c * 8;
  }
  const int ldsoff = (tid >> 3) * 64 + (tid & 7) * 8; // == tid*8 elements, per-wave uniform base below
  (void)ldsoff;

  const int lrow = lane & 15, q = lane >> 4;
  const int cxor = lrow & 7;                  // row&7 for all fragment rows (row = 16*k + lrow)

  f32x4 acc[8][4];
  #pragma unroll
  for (int m = 0; m < 8; m++)
    #pragma unroll
    for (int n = 0; n < 4; n++) acc[m][n] = (f32x4){0.f, 0.f, 0.f, 0.f};

  const int NKT = DD / 64;                    // 16 K-tiles
  // prologue: stage tile 0 -> buf 0
  #pragma unroll
  for (int g = 0; g < 4; g++) {
    gload16(gAp[g], &sA[0][0] + g * 4096 + wid * 512);
    gload16(gBp[g], &sB[0][0] + g * 4096 + wid * 512);
  }

  for (int T = 0; T < NKT; T++) {
    const int cur = T & 1;
    const int Tn = (T + 1 == NKT) ? 0 : T + 1; // wrap: last prefetch redundant but harmless
    const int koff = Tn * 64;
    // stage tile T+1 into buf[cur^1] (8 vmcnt increments per wave)
    #pragma unroll
    for (int g = 0; g < 4; g++) {
      gload16(gAp[g] + koff, &sA[cur ^ 1][0] + g * 4096 + wid * 512);
      gload16(gBp[g] + koff, &sB[cur ^ 1][0] + g * 4096 + wid * 512);
    }
    // wait ONLY for tile T's 8 loads (oldest); T+1's 8 stay in flight
    asm volatile("s_waitcnt vmcnt(8)" ::: "memory");
    __syncthreads();
    const char* bA = reinterpret_cast<const char*>(&sA[cur][0]);
    const char* bB = reinterpret_cast<const char*>(&sB[cur][0]);
    #pragma unroll
    for (int ph = 0; ph < 4; ph++) {
      const int mh = ph >> 1, nh = ph & 1;
      bf16x8 af[4][2], bfr[2][2];
      #pragma unroll
      for (int mi = 0; mi < 4; mi++) {
        const int row = wr * 128 + (mh * 4 + mi) * 16 + lrow;
        #pragma unroll
        for (int kk = 0; kk < 2; kk++)
          af[mi][kk] = *reinterpret_cast<const bf16x8*>(bA + row * 128 + ((((kk << 2) + q) ^ cxor) << 4));
      }
      #pragma unroll
      for (int ni = 0; ni < 2; ni++) {
        const int brow = wcn * 64 + (nh * 2 + ni) * 16 + lrow;
        #pragma unroll
        for (int kk = 0; kk < 2; kk++)
          bfr[ni][kk] = *reinterpret_cast<const bf16x8*>(bB + brow * 128 + ((((kk << 2) + q) ^ cxor) << 4));
      }
      __builtin_amdgcn_s_setprio(1);
      #pragma unroll
      for (int mi = 0; mi < 4; mi++)
        #pragma unroll
        for (int ni = 0; ni < 2; ni++)
          #pragma unroll
          for (int kk = 0; kk < 2; kk++)
            acc[mh * 4 + mi][nh * 2 + ni] =
                __builtin_amdgcn_mfma_f32_16x16x32_bf16(af[mi][kk], bfr[ni][kk],
                                                        acc[mh * 4 + mi][nh * 2 + ni], 0, 0, 0);
      __builtin_amdgcn_s_setprio(0);
      __builtin_amdgcn_sched_barrier(0);
    }
    __syncthreads();   // all reads of buf[cur] done before next iter stages into it
  }

  // epilogue: pair interleaved cols (n even = a, n odd = b of same f-group)
  #pragma unroll
  for (int np = 0; np < 2; np++) {
    const int f = (c0 >> 1) + wcn * 32 + np * 16 + lrow;
    const float ba_ = b1a[e * FF + f], bb_ = b1b[e * FF + f];
    #pragma unroll
    for (int m = 0; m < 8; m++) {
      #pragma unroll
      for (int r = 0; r < 4; r++) {
        const float a = acc[m][2 * np][r] + ba_;
        const float b = acc[m][2 * np + 1][r] + bb_;
        const float h = (a / (1.0f + __expf(-a))) * b;
        const int grow = row0 + wr * 128 + m * 16 + q * 4 + r;
        H[(size_t)grow * FF + f] = f2bf(h);
      }
    }
  }
}

// ---------------- grouped GEMM2 (m97 structure): Y[row] = H@W2 + b2 (dense stores) ----------------
__global__ __launch_bounds__(256) void k_ffn2(
    const ushort* __restrict__ H, const ushort* __restrict__ W2T, const float* __restrict__ b2,
    const int* __restrict__ base, float* __restrict__ Y) {
  const int row0 = blockIdx.y * 128;
  if (row0 >= base[EE]) return;
  int e = 0;
  while (e < EE - 1 && row0 >= base[e + 1]) e++;
  const int d0 = blockIdx.x * 128;
  const int tid = threadIdx.x, wid = tid >> 6, lane = tid & 63;
  const int wr = wid >> 1, wc = wid & 1;
  __shared__ ushort sA[128 * 32], sB[128 * 32];
  const int rloc = tid >> 2;
  const int kcol = (((tid & 3) * 16) ^ swz_of_row(rloc)) >> 1;
  const ushort* gA0 = H + (size_t)(row0 + rloc) * FF + kcol;
  const ushort* gA1 = H + (size_t)(row0 + 64 + rloc) * FF + kcol;
  const ushort* gB0 = W2T + ((size_t)e * DD + d0 + rloc) * FF + kcol;
  const ushort* gB1 = W2T + ((size_t)e * DD + d0 + 64 + rloc) * FF + kcol;
  ushort* lA0 = sA + wid * 512;  ushort* lA1 = sA + 2048 + wid * 512;
  ushort* lB0 = sB + wid * 512;  ushort* lB1 = sB + 2048 + wid * 512;
  const int lrow = lane & 15, q = lane >> 4;
  const int fsw = (q * 16) ^ swz_of_row(lrow);
  int aoff[4], boff[4];
  #pragma unroll
  for (int m = 0; m < 4; m++) aoff[m] = (wr * 64 + m * 16 + lrow) * 64 + fsw;
  #pragma unroll
  for (int n = 0; n < 4; n++) boff[n] = (wc * 64 + n * 16 + lrow) * 64 + fsw;
  f32x4 acc[16];
  #pragma unroll
  for (int i = 0; i < 16; i++) acc[i] = (f32x4){0.f, 0.f, 0.f, 0.f};
  for (int kt = 0; kt < FF / 32; kt++) {
    gload16(gA0 + kt * 32, lA0);
    gload16(gA1 + kt * 32, lA1);
    gload16(gB0 + kt * 32, lB0);
    gload16(gB1 + kt * 32, lB1);
    __syncthreads();
    bf16x8 fb[4];
    #pragma unroll
    for (int n = 0; n < 4; n++)
      fb[n] = *reinterpret_cast<const bf16x8*>(reinterpret_cast<const char*>(sB) + boff[n]);
    #pragma unroll
    for (int m = 0; m < 4; m++) {
      const bf16x8 fa = *reinterpret_cast<const bf16x8*>(reinterpret_cast<const char*>(sA) + aoff[m]);
      #pragma unroll
      for (int n = 0; n < 4; n++)
        acc[m * 4 + n] = __builtin_amdgcn_mfma_f32_16x16x32_bf16(fa, fb[n], acc[m * 4 + n], 0, 0, 0);
    }
    __syncthreads();
  }
  #pragma unroll
  for (int n = 0; n < 4; n++) {
    const int dcol = d0 + wc * 64 + n * 16 + lrow;
    const float bias = b2[e * DD + dcol];
    #pragma unroll
    for (int m = 0; m < 4; m++) {
      #pragma unroll
      for (int r = 0; r < 4; r++) {
        const int grow = row0 + wr * 64 + m * 16 + q * 4 + r;
        Y[(size_t)grow * DD + dcol] = acc[m * 4 + n][r] + bias;
      }
    }
  }
}

// ---------------- gather: out[t] = w0*Y[r0] + w1*Y[r1] ----------------
__global__ __launch_bounds__(256) void k_gather(
    const float* __restrict__ Y, const int* __restrict__ rows_of_tok,
    const float* __restrict__ tk_w, float* __restrict__ out0) {
  const int t = blockIdx.x;
  const int r0 = rows_of_tok[2 * t], r1 = rows_of_tok[2 * t + 1];
  const float w0 = tk_w[2 * t], w1 = tk_w[2 * t + 1];
  const float4 y0 = reinterpret_cast<const float4*>(Y + (size_t)r0 * DD)[threadIdx.x];
  const float4 y1 = reinterpret_cast<const float4*>(Y + (size_t)r1 * DD)[threadIdx.x];
  float4 o;
  o.x = w0 * y0.x + w1 * y1.x;
  o.y = w0 * y0.y + w1 * y1.y;
  o.z = w0 * y0.z + w1 * y1.z;
  o.w = w0 * y0.w + w1 * y1.w;
  reinterpret_cast<float4*>(out0 + (size_t)t * DD)[threadIdx.x] = o;
}

// ---------------- workspace layout (bytes); total ~193.2 MB ----------------
// Y (fp32 [NRCAP*DD] = 75,497,472) aliases XN+BT1 (83.9 MB, dead by ffn2 time).
#define WS_Y    ((size_t)0)
#define WS_XN   ((size_t)0)                    // bf16 [NT*DD]          16,777,216
#define WS_BT1  ((size_t)16777216)             // bf16 [EE*4096*DD]     67,108,864
#define WS_W2T  ((size_t)83886080)             // bf16 [EE*DD*FF]       33,554,432
#define WS_H    ((size_t)117440512)            // bf16 [NRCAP*FF]       75,497,472
#define WS_TOK  ((size_t)192937984)            // int  [NRCAP]
#define WS_ROWS ((size_t)193011712)            // int  [2*NT]
#define WS_TKE  ((size_t)193077248)            // int  [NT]
#define WS_TKW  ((size_t)193110016)            // f32  [2*NT]
#define WS_CNT  ((size_t)193175552)            // int  [8]
#define WS_BASE ((size_t)193175616)            // int  [9]
#define WS_CUR  ((size_t)193175680)            // int  [8]

extern "C" void kernel_launch(void* const* d_in, const int* in_sizes, int n_in,
                              void* d_out, int out_size, void* d_ws, size_t ws_size,
                              hipStream_t stream) {
  const float* x     = (const float*)d_in[0];
  const float* rms_w = (const float*)d_in[1];
  const float* Wg    = (const float*)d_in[2];
  const float* bg    = (const float*)d_in[3];
  const float* W1a   = (const float*)d_in[4];
  const float* b1a   = (const float*)d_in[5];
  const float* W1b   = (const float*)d_in[6];
  const float* b1b   = (const float*)d_in[7];
  const float* W2    = (const float*)d_in[8];
  const float* b2    = (const float*)d_in[9];
  float* out0 = (float*)d_out;                       // [NT*DD]
  float* outW = (float*)d_out + (size_t)NT * DD;     // [NT*EE]

  char* ws = (char*)d_ws;
  ushort* xn    = (ushort*)(ws + WS_XN);
  ushort* BT1   = (ushort*)(ws + WS_BT1);
  ushort* W2T   = (ushort*)(ws + WS_W2T);
  ushort* Hbuf  = (ushort*)(ws + WS_H);
  float*  Ybuf  = (float*)(ws + WS_Y);
  int*    tok   = (int*)(ws + WS_TOK);
  int*    rows  = (int*)(ws + WS_ROWS);
  int*    tk_e  = (int*)(ws + WS_TKE);
  float*  tk_w  = (float*)(ws + WS_TKW);
  int*    cnt   = (int*)(ws + WS_CNT);
  int*    base  = (int*)(ws + WS_BASE);
  int*    cur   = (int*)(ws + WS_CUR);

  hipMemsetAsync(cnt, 0, 8 * sizeof(int), stream);

  // weight transpose+cast (every launch; weights are inputs)
  k_transpose_pair64<<<dim3(FF / 64, DD / 64, EE), 256, 0, stream>>>(W1a, BT1, 0);
  k_transpose_pair64<<<dim3(FF / 64, DD / 64, EE), 256, 0, stream>>>(W1b, BT1, 1);
  k_transpose64<<<dim3(DD / 64, FF / 64, EE), 256, 0, stream>>>(W2, W2T, FF, DD);

  k_rms_gate<<<NT, 256, 0, stream>>>(x, rms_w, Wg, bg, xn, outW, tk_e, tk_w, cnt);
  k_scan<<<1, 256, 0, stream>>>(cnt, base, cur, tok);
  k_scatter<<<NT / 256, 256, 0, stream>>>(tk_e, base, cur, tok, rows);

  k_ffn1<<<dim3(4096 / 256, MAXT256), 512, 0, stream>>>(xn, BT1, b1a, b1b, tok, base, Hbuf);
  k_ffn2<<<dim3(DD / 128, MAXT128), 256, 0, stream>>>(Hbuf, W2T, b2, base, Ybuf);
  k_gather<<<NT, 256, 0, stream>>>(Ybuf, rows, tk_w, out0);
}

// Round 5
// 653.064 us; speedup vs baseline: 1.0234x; 1.0234x over previous
//
#include <hip/hip_runtime.h>
#include <hip/hip_bf16.h>

// SMoE: B=4 S=2048 D=1024 F=2048 E=8 K=2
#define DD 1024
#define FF 2048
#define EE 8
#define NT 8192            // B*S tokens
#define NRCAP 18432        // 72 tiles of 256 rows (16384 + 8*255 max pad)
#define MAXT256 72
#define MAXT128 144

typedef __attribute__((ext_vector_type(8))) short bf16x8;
typedef __attribute__((ext_vector_type(4))) float f32x4;

__device__ __forceinline__ ushort f2bf(float f) {
  __hip_bfloat16 h = __float2bfloat16(f);
  return *reinterpret_cast<ushort*>(&h);
}

__device__ __forceinline__ void gload16(const void* g, void* l) {
  __builtin_amdgcn_global_load_lds((const __attribute__((address_space(1))) void*)g,
                                   (__attribute__((address_space(3))) void*)l, 16, 0, 0);
}

// legacy 4-slot swizzle (BK=32 kernels: ffn2)
__device__ __forceinline__ int swz_of_row(int r) { return ((r >> 1) & 3) << 4; }

// ---------------- 64x64 vectorized transpose+cast: f32 [E][R][C] -> bf16 [E][C][R]
__global__ __launch_bounds__(256) void k_transpose64(const float* __restrict__ in,
                                                     ushort* __restrict__ outT, int R, int C) {
  __shared__ ushort tile[64][68];
  const int e = blockIdx.z;
  const int c0 = blockIdx.x * 64, r0 = blockIdx.y * 64;
  const float* ip = in + (size_t)e * R * C;
  const int cq = threadIdx.x & 15, rr = threadIdx.x >> 4;
  #pragma unroll
  for (int p = 0; p < 4; p++) {
    const int r = rr + 16 * p;
    float4 v = *reinterpret_cast<const float4*>(ip + (size_t)(r0 + r) * C + c0 + 4 * cq);
    ushort4 u = make_ushort4(f2bf(v.x), f2bf(v.y), f2bf(v.z), f2bf(v.w));
    *reinterpret_cast<ushort4*>(&tile[r][4 * cq]) = u;
  }
  __syncthreads();
  ushort* op = outT + (size_t)e * C * R;
  const int rq = threadIdx.x & 15, cc = threadIdx.x >> 4;
  #pragma unroll
  for (int p = 0; p < 4; p++) {
    const int c = cc + 16 * p;
    ushort4 u = make_ushort4(tile[4 * rq + 0][c], tile[4 * rq + 1][c],
                             tile[4 * rq + 2][c], tile[4 * rq + 3][c]);
    *reinterpret_cast<ushort4*>(op + (size_t)(c0 + c) * R + r0 + 4 * rq) = u;
  }
}

// ---------------- interleaving 64x64 transpose for W1a/W1b -> BT1 [E][4096][D]
__global__ __launch_bounds__(256) void k_transpose_pair64(const float* __restrict__ in,
                                                          ushort* __restrict__ outT, int half) {
  __shared__ ushort tile[64][68];
  const int e = blockIdx.z;
  const int f0 = blockIdx.x * 64, d0 = blockIdx.y * 64;
  const float* ip = in + (size_t)e * DD * FF;
  const int cq = threadIdx.x & 15, rr = threadIdx.x >> 4;
  #pragma unroll
  for (int p = 0; p < 4; p++) {
    const int r = rr + 16 * p;
    float4 v = *reinterpret_cast<const float4*>(ip + (size_t)(d0 + r) * FF + f0 + 4 * cq);
    ushort4 u = make_ushort4(f2bf(v.x), f2bf(v.y), f2bf(v.z), f2bf(v.w));
    *reinterpret_cast<ushort4*>(&tile[r][4 * cq]) = u;
  }
  __syncthreads();
  ushort* op = outT + (size_t)e * 4096 * DD;
  const int rq = threadIdx.x & 15, cc = threadIdx.x >> 4;
  #pragma unroll
  for (int p = 0; p < 4; p++) {
    const int f = f0 + cc + 16 * p;
    const int rmap = ((f >> 4) << 5) + half * 16 + (f & 15);
    ushort4 u = make_ushort4(tile[4 * rq + 0][cc + 16 * p], tile[4 * rq + 1][cc + 16 * p],
                             tile[4 * rq + 2][cc + 16 * p], tile[4 * rq + 3][cc + 16 * p]);
    *reinterpret_cast<ushort4*>(op + (size_t)rmap * DD + d0 + 4 * rq) = u;
  }
}

// ---------------- RMSNorm + gating (one block per token) ----------------
__global__ __launch_bounds__(256) void k_rms_gate(
    const float* __restrict__ x, const float* __restrict__ rms_w,
    const float* __restrict__ Wg, const float* __restrict__ bg,
    ushort* __restrict__ xn, float* __restrict__ outW,
    int* __restrict__ tk_e, float* __restrict__ tk_w, int* __restrict__ counts) {
  const int t = blockIdx.x, tid = threadIdx.x;
  const int wid = tid >> 6, lane = tid & 63;
  const float4 xv = reinterpret_cast<const float4*>(x + (size_t)t * DD)[tid];
  float ss = xv.x * xv.x + xv.y * xv.y + xv.z * xv.z + xv.w * xv.w;
  #pragma unroll
  for (int m = 32; m; m >>= 1) ss += __shfl_xor(ss, m);
  __shared__ float sred[4];
  __shared__ float slog[4][8];
  if (lane == 0) sred[wid] = ss;
  __syncthreads();
  const float ms = (sred[0] + sred[1] + sred[2] + sred[3]) * (1.0f / (float)DD);
  const float sc = 1.0f / sqrtf(ms + 1.1920929e-07f);   // finfo(f32).eps
  const float4 wv = reinterpret_cast<const float4*>(rms_w)[tid];
  float xs[4] = { xv.x * sc * wv.x, xv.y * sc * wv.y, xv.z * sc * wv.z, xv.w * sc * wv.w };
  ushort4 st = make_ushort4(f2bf(xs[0]), f2bf(xs[1]), f2bf(xs[2]), f2bf(xs[3]));
  reinterpret_cast<ushort4*>(xn + (size_t)t * DD)[tid] = st;
  float lg[8] = {0.f, 0.f, 0.f, 0.f, 0.f, 0.f, 0.f, 0.f};
  const float4* Wg4 = reinterpret_cast<const float4*>(Wg);
  const int d = tid * 4;
  #pragma unroll
  for (int j = 0; j < 4; j++) {
    float4 wa = Wg4[(d + j) * 2];
    float4 wb = Wg4[(d + j) * 2 + 1];
    lg[0] += xs[j] * wa.x; lg[1] += xs[j] * wa.y; lg[2] += xs[j] * wa.z; lg[3] += xs[j] * wa.w;
    lg[4] += xs[j] * wb.x; lg[5] += xs[j] * wb.y; lg[6] += xs[j] * wb.z; lg[7] += xs[j] * wb.w;
  }
  #pragma unroll
  for (int m = 32; m; m >>= 1) {
    #pragma unroll
    for (int i = 0; i < 8; i++) lg[i] += __shfl_xor(lg[i], m);
  }
  if (lane == 0) {
    #pragma unroll
    for (int i = 0; i < 8; i++) slog[wid][i] = lg[i];
  }
  __syncthreads();
  if (tid == 0) {
    float l[8];
    for (int i = 0; i < 8; i++)
      l[i] = slog[0][i] + slog[1][i] + slog[2][i] + slog[3][i] + bg[i];
    int i0 = 0; float v0 = l[0];
    for (int i = 1; i < 8; i++) if (l[i] > v0) { v0 = l[i]; i0 = i; }   // first max (jax tie rule)
    int i1 = -1; float v1 = -3.4e38f;
    for (int i = 0; i < 8; i++) if (i != i0 && l[i] > v1) { v1 = l[i]; i1 = i; }
    const float e1v = __expf(v1 - v0);
    const float w0 = 1.0f / (1.0f + e1v);
    const float w1 = e1v * w0;
    float* wrow = outW + (size_t)t * EE;
    for (int i = 0; i < 8; i++) wrow[i] = 0.f;
    wrow[i0] = w0; wrow[i1] = w1;
    tk_e[t] = i0 | (i1 << 8);
    tk_w[2 * t] = w0; tk_w[2 * t + 1] = w1;
    atomicAdd(&counts[i0], 1);
    atomicAdd(&counts[i1], 1);
  }
}

// ---------------- scan counts -> 256-aligned bases; init row map ----------------
__global__ void k_scan(const int* __restrict__ counts, int* __restrict__ base,
                       int* __restrict__ cursors, int* __restrict__ tok_of_row) {
  if (threadIdx.x == 0) {
    int acc = 0;
    for (int e = 0; e < EE; e++) {
      base[e] = acc;
      cursors[e] = 0;
      acc += ((counts[e] + 255) >> 8) << 8;
    }
    base[EE] = acc;
  }
  for (int i = threadIdx.x; i < NRCAP; i += 256) tok_of_row[i] = -1;
}

// ---------------- scatter tokens into expert-grouped rows ----------------
__global__ __launch_bounds__(256) void k_scatter(
    const int* __restrict__ tk_e, const int* __restrict__ base, int* __restrict__ cursors,
    int* __restrict__ tok_of_row, int* __restrict__ rows_of_tok) {
  const int t = blockIdx.x * 256 + threadIdx.x;
  if (t >= NT) return;
  const int ee = tk_e[t];
  const int e0 = ee & 255, e1 = (ee >> 8) & 255;
  int s = atomicAdd(&cursors[e0], 1);
  int row = base[e0] + s;
  tok_of_row[row] = t; rows_of_tok[2 * t] = row;
  s = atomicAdd(&cursors[e1], 1);
  row = base[e1] + s;
  tok_of_row[row] = t; rows_of_tok[2 * t + 1] = row;
}

// ---------------- grouped GEMM1: 256x256 tile, BK=64, 8 waves, deep pipeline ----------------
// dbuf LDS (128 KiB). RAW s_barrier (no implicit vmcnt drain — the R4 bug was
// __syncthreads' vmcnt(0) drain killing the prefetch). Counted s_waitcnt vmcnt(8):
// tile T+1's 8 global_load_lds stay in flight across both barriers.
// LDS layout: [row][slot] with slot = chunk ^ (row&7), chunk = 16B column group.
__global__ __launch_bounds__(512, 2) void k_ffn1(
    const ushort* __restrict__ xn, const ushort* __restrict__ BT1,
    const float* __restrict__ b1a, const float* __restrict__ b1b,
    const int* __restrict__ tok_of_row, const int* __restrict__ base,
    ushort* __restrict__ H) {
  const int row0 = blockIdx.y * 256;
  if (row0 >= base[EE]) return;
  int e = 0;
  while (e < EE - 1 && row0 >= base[e + 1]) e++;
  const int c0 = blockIdx.x * 256;            // interleaved column base
  const int tid = threadIdx.x;                // 0..511
  const int wid = tid >> 6, lane = tid & 63;
  const int wr = wid >> 2, wcn = wid & 3;     // 2 M-waves x 4 N-waves; wave out = 128x64
  __shared__ ushort sA[2][256 * 64];          // 2 x 32 KiB
  __shared__ ushort sB[2][256 * 64];          // 2 x 32 KiB

  // ---- staging map: issue g covers tile rows g*64..g*64+63; thread -> (row, slot)
  const int rS = tid >> 3;                    // 0..63
  const int slot = tid & 7;
  const ushort* gAp[4];
  const ushort* gBp[4];
  #pragma unroll
  for (int g = 0; g < 4; g++) {
    const int R = g * 64 + rS;
    int tok = tok_of_row[row0 + R]; if (tok < 0) tok = 0;
    const int c = slot ^ (R & 7);             // pre-swizzled global chunk
    gAp[g] = xn + (size_t)tok * DD + c * 8;
    gBp[g] = BT1 + ((size_t)e * 4096 + c0 + R) * DD + c * 8;
  }

  const int lrow = lane & 15, q = lane >> 4;
  const int cxor = lrow & 7;                  // row&7 for all fragment rows (row = 16*k + lrow)

  f32x4 acc[8][4];
  #pragma unroll
  for (int m = 0; m < 8; m++)
    #pragma unroll
    for (int n = 0; n < 4; n++) acc[m][n] = (f32x4){0.f, 0.f, 0.f, 0.f};

  const int NKT = DD / 64;                    // 16 K-tiles
  // prologue: stage tile 0 -> buf 0 (8 loads in flight)
  #pragma unroll
  for (int g = 0; g < 4; g++) {
    gload16(gAp[g], &sA[0][0] + g * 4096 + wid * 512);
    gload16(gBp[g], &sB[0][0] + g * 4096 + wid * 512);
  }

  for (int T = 0; T < NKT; T++) {
    const int cur = T & 1;
    const int Tn = (T + 1 == NKT) ? 0 : T + 1; // wrap: last prefetch redundant but harmless
    const int koff = Tn * 64;
    // stage tile T+1 into buf[cur^1] (8 more loads; 16 in flight)
    #pragma unroll
    for (int g = 0; g < 4; g++) {
      gload16(gAp[g] + koff, &sA[cur ^ 1][0] + g * 4096 + wid * 512);
      gload16(gBp[g] + koff, &sB[cur ^ 1][0] + g * 4096 + wid * 512);
    }
    // wait ONLY for tile T's 8 loads (oldest); T+1's 8 stay in flight.
    asm volatile("s_waitcnt vmcnt(8)" ::: "memory");
    __builtin_amdgcn_s_barrier();   // RAW barrier: no implicit vmcnt(0) drain
    const char* bA = reinterpret_cast<const char*>(&sA[cur][0]);
    const char* bB = reinterpret_cast<const char*>(&sB[cur][0]);
    #pragma unroll
    for (int ph = 0; ph < 4; ph++) {
      const int mh = ph >> 1, nh = ph & 1;
      bf16x8 af[4][2], bfr[2][2];
      #pragma unroll
      for (int mi = 0; mi < 4; mi++) {
        const int row = wr * 128 + (mh * 4 + mi) * 16 + lrow;
        #pragma unroll
        for (int kk = 0; kk < 2; kk++)
          af[mi][kk] = *reinterpret_cast<const bf16x8*>(bA + row * 128 + ((((kk << 2) + q) ^ cxor) << 4));
      }
      #pragma unroll
      for (int ni = 0; ni < 2; ni++) {
        const int brow = wcn * 64 + (nh * 2 + ni) * 16 + lrow;
        #pragma unroll
        for (int kk = 0; kk < 2; kk++)
          bfr[ni][kk] = *reinterpret_cast<const bf16x8*>(bB + brow * 128 + ((((kk << 2) + q) ^ cxor) << 4));
      }
      __builtin_amdgcn_s_setprio(1);
      #pragma unroll
      for (int mi = 0; mi < 4; mi++)
        #pragma unroll
        for (int ni = 0; ni < 2; ni++)
          #pragma unroll
          for (int kk = 0; kk < 2; kk++)
            acc[mh * 4 + mi][nh * 2 + ni] =
                __builtin_amdgcn_mfma_f32_16x16x32_bf16(af[mi][kk], bfr[ni][kk],
                                                        acc[mh * 4 + mi][nh * 2 + ni], 0, 0, 0);
      __builtin_amdgcn_s_setprio(0);
      __builtin_amdgcn_sched_barrier(0);
    }
    // all waves' LDS reads are in registers (compiler lgkmcnt before MFMA use);
    // barrier orders them before next iter's staging overwrites buf[cur].
    __builtin_amdgcn_s_barrier();
  }

  // epilogue: pair interleaved cols (n even = a, n odd = b of same f-group)
  #pragma unroll
  for (int np = 0; np < 2; np++) {
    const int f = (c0 >> 1) + wcn * 32 + np * 16 + lrow;
    const float ba_ = b1a[e * FF + f], bb_ = b1b[e * FF + f];
    #pragma unroll
    for (int m = 0; m < 8; m++) {
      #pragma unroll
      for (int r = 0; r < 4; r++) {
        const float a = acc[m][2 * np][r] + ba_;
        const float b = acc[m][2 * np + 1][r] + bb_;
        const float h = (a / (1.0f + __expf(-a))) * b;
        const int grow = row0 + wr * 128 + m * 16 + q * 4 + r;
        H[(size_t)grow * FF + f] = f2bf(h);
      }
    }
  }
}

// ---------------- grouped GEMM2 (m97 structure): Y[row] = H@W2 + b2 (dense stores) ----------------
__global__ __launch_bounds__(256) void k_ffn2(
    const ushort* __restrict__ H, const ushort* __restrict__ W2T, const float* __restrict__ b2,
    const int* __restrict__ base, float* __restrict__ Y) {
  const int row0 = blockIdx.y * 128;
  if (row0 >= base[EE]) return;
  int e = 0;
  while (e < EE - 1 && row0 >= base[e + 1]) e++;
  const int d0 = blockIdx.x * 128;
  const int tid = threadIdx.x, wid = tid >> 6, lane = tid & 63;
  const int wr = wid >> 1, wc = wid & 1;
  __shared__ ushort sA[128 * 32], sB[128 * 32];
  const int rloc = tid >> 2;
  const int kcol = (((tid & 3) * 16) ^ swz_of_row(rloc)) >> 1;
  const ushort* gA0 = H + (size_t)(row0 + rloc) * FF + kcol;
  const ushort* gA1 = H + (size_t)(row0 + 64 + rloc) * FF + kcol;
  const ushort* gB0 = W2T + ((size_t)e * DD + d0 + rloc) * FF + kcol;
  const ushort* gB1 = W2T + ((size_t)e * DD + d0 + 64 + rloc) * FF + kcol;
  ushort* lA0 = sA + wid * 512;  ushort* lA1 = sA + 2048 + wid * 512;
  ushort* lB0 = sB + wid * 512;  ushort* lB1 = sB + 2048 + wid * 512;
  const int lrow = lane & 15, q = lane >> 4;
  const int fsw = (q * 16) ^ swz_of_row(lrow);
  int aoff[4], boff[4];
  #pragma unroll
  for (int m = 0; m < 4; m++) aoff[m] = (wr * 64 + m * 16 + lrow) * 64 + fsw;
  #pragma unroll
  for (int n = 0; n < 4; n++) boff[n] = (wc * 64 + n * 16 + lrow) * 64 + fsw;
  f32x4 acc[16];
  #pragma unroll
  for (int i = 0; i < 16; i++) acc[i] = (f32x4){0.f, 0.f, 0.f, 0.f};
  for (int kt = 0; kt < FF / 32; kt++) {
    gload16(gA0 + kt * 32, lA0);
    gload16(gA1 + kt * 32, lA1);
    gload16(gB0 + kt * 32, lB0);
    gload16(gB1 + kt * 32, lB1);
    __syncthreads();
    bf16x8 fb[4];
    #pragma unroll
    for (int n = 0; n < 4; n++)
      fb[n] = *reinterpret_cast<const bf16x8*>(reinterpret_cast<const char*>(sB) + boff[n]);
    #pragma unroll
    for (int m = 0; m < 4; m++) {
      const bf16x8 fa = *reinterpret_cast<const bf16x8*>(reinterpret_cast<const char*>(sA) + aoff[m]);
      #pragma unroll
      for (int n = 0; n < 4; n++)
        acc[m * 4 + n] = __builtin_amdgcn_mfma_f32_16x16x32_bf16(fa, fb[n], acc[m * 4 + n], 0, 0, 0);
    }
    __syncthreads();
  }
  #pragma unroll
  for (int n = 0; n < 4; n++) {
    const int dcol = d0 + wc * 64 + n * 16 + lrow;
    const float bias = b2[e * DD + dcol];
    #pragma unroll
    for (int m = 0; m < 4; m++) {
      #pragma unroll
      for (int r = 0; r < 4; r++) {
        const int grow = row0 + wr * 64 + m * 16 + q * 4 + r;
        Y[(size_t)grow * DD + dcol] = acc[m * 4 + n][r] + bias;
      }
    }
  }
}

// ---------------- gather: out[t] = w0*Y[r0] + w1*Y[r1] ----------------
__global__ __launch_bounds__(256) void k_gather(
    const float* __restrict__ Y, const int* __restrict__ rows_of_tok,
    const float* __restrict__ tk_w, float* __restrict__ out0) {
  const int t = blockIdx.x;
  const int r0 = rows_of_tok[2 * t], r1 = rows_of_tok[2 * t + 1];
  const float w0 = tk_w[2 * t], w1 = tk_w[2 * t + 1];
  const float4 y0 = reinterpret_cast<const float4*>(Y + (size_t)r0 * DD)[threadIdx.x];
  const float4 y1 = reinterpret_cast<const float4*>(Y + (size_t)r1 * DD)[threadIdx.x];
  float4 o;
  o.x = w0 * y0.x + w1 * y1.x;
  o.y = w0 * y0.y + w1 * y1.y;
  o.z = w0 * y0.z + w1 * y1.z;
  o.w = w0 * y0.w + w1 * y1.w;
  reinterpret_cast<float4*>(out0 + (size_t)t * DD)[threadIdx.x] = o;
}

// ---------------- workspace layout (bytes); total ~193.2 MB ----------------
// Y (fp32 [NRCAP*DD] = 75,497,472) aliases XN+BT1 (83.9 MB, dead by ffn2 time).
#define WS_Y    ((size_t)0)
#define WS_XN   ((size_t)0)                    // bf16 [NT*DD]          16,777,216
#define WS_BT1  ((size_t)16777216)             // bf16 [EE*4096*DD]     67,108,864
#define WS_W2T  ((size_t)83886080)             // bf16 [EE*DD*FF]       33,554,432
#define WS_H    ((size_t)117440512)            // bf16 [NRCAP*FF]       75,497,472
#define WS_TOK  ((size_t)192937984)            // int  [NRCAP]
#define WS_ROWS ((size_t)193011712)            // int  [2*NT]
#define WS_TKE  ((size_t)193077248)            // int  [NT]
#define WS_TKW  ((size_t)193110016)            // f32  [2*NT]
#define WS_CNT  ((size_t)193175552)            // int  [8]
#define WS_BASE ((size_t)193175616)            // int  [9]
#define WS_CUR  ((size_t)193175680)            // int  [8]

extern "C" void kernel_launch(void* const* d_in, const int* in_sizes, int n_in,
                              void* d_out, int out_size, void* d_ws, size_t ws_size,
                              hipStream_t stream) {
  const float* x     = (const float*)d_in[0];
  const float* rms_w = (const float*)d_in[1];
  const float* Wg    = (const float*)d_in[2];
  const float* bg    = (const float*)d_in[3];
  const float* W1a   = (const float*)d_in[4];
  const float* b1a   = (const float*)d_in[5];
  const float* W1b   = (const float*)d_in[6];
  const float* b1b   = (const float*)d_in[7];
  const float* W2    = (const float*)d_in[8];
  const float* b2    = (const float*)d_in[9];
  float* out0 = (float*)d_out;                       // [NT*DD]
  float* outW = (float*)d_out + (size_t)NT * DD;     // [NT*EE]

  char* ws = (char*)d_ws;
  ushort* xn    = (ushort*)(ws + WS_XN);
  ushort* BT1   = (ushort*)(ws + WS_BT1);
  ushort* W2T   = (ushort*)(ws + WS_W2T);
  ushort* Hbuf  = (ushort*)(ws + WS_H);
  float*  Ybuf  = (float*)(ws + WS_Y);
  int*    tok   = (int*)(ws + WS_TOK);
  int*    rows  = (int*)(ws + WS_ROWS);
  int*    tk_e  = (int*)(ws + WS_TKE);
  float*  tk_w  = (float*)(ws + WS_TKW);
  int*    cnt   = (int*)(ws + WS_CNT);
  int*    base  = (int*)(ws + WS_BASE);
  int*    cur   = (int*)(ws + WS_CUR);

  hipMemsetAsync(cnt, 0, 8 * sizeof(int), stream);

  // weight transpose+cast (every launch; weights are inputs)
  k_transpose_pair64<<<dim3(FF / 64, DD / 64, EE), 256, 0, stream>>>(W1a, BT1, 0);
  k_transpose_pair64<<<dim3(FF / 64, DD / 64, EE), 256, 0, stream>>>(W1b, BT1, 1);
  k_transpose64<<<dim3(DD / 64, FF / 64, EE), 256, 0, stream>>>(W2, W2T, FF, DD);

  k_rms_gate<<<NT, 256, 0, stream>>>(x, rms_w, Wg, bg, xn, outW, tk_e, tk_w, cnt);
  k_scan<<<1, 256, 0, stream>>>(cnt, base, cur, tok);
  k_scatter<<<NT / 256, 256, 0, stream>>>(tk_e, base, cur, tok, rows);

  k_ffn1<<<dim3(4096 / 256, MAXT256), 512, 0, stream>>>(xn, BT1, b1a, b1b, tok, base, Hbuf);
  k_ffn2<<<dim3(DD / 128, MAXT128), 256, 0, stream>>>(Hbuf, W2T, b2, base, Ybuf);
  k_gather<<<NT, 256, 0, stream>>>(Ybuf, rows, tk_w, out0);
}

// Round 6
// 642.904 us; speedup vs baseline: 1.0396x; 1.0158x over previous
//
#include <hip/hip_runtime.h>
#include <hip/hip_bf16.h>

// SMoE: B=4 S=2048 D=1024 F=2048 E=8 K=2
#define DD 1024
#define FF 2048
#define EE 8
#define NT 8192            // B*S tokens
#define NRCAP 18432        // 72 tiles of 256 rows (16384 + 8*255 max pad)
#define MAXT256 72
#define MAXT128 144

typedef __attribute__((ext_vector_type(8))) short bf16x8;
typedef __attribute__((ext_vector_type(4))) float f32x4;

__device__ __forceinline__ ushort f2bf(float f) {
  __hip_bfloat16 h = __float2bfloat16(f);
  return *reinterpret_cast<ushort*>(&h);
}

__device__ __forceinline__ void gload16(const void* g, void* l) {
  __builtin_amdgcn_global_load_lds((const __attribute__((address_space(1))) void*)g,
                                   (__attribute__((address_space(3))) void*)l, 16, 0, 0);
}

// 4-slot XOR swizzle for [row][32 bf16] LDS tiles (verified R1-R3: 0 bank conflicts)
__device__ __forceinline__ int swz_of_row(int r) { return ((r >> 1) & 3) << 4; }

// ---------------- 64x64 vectorized transpose+cast: f32 [E][R][C] -> bf16 [E][C][R]
__global__ __launch_bounds__(256) void k_transpose64(const float* __restrict__ in,
                                                     ushort* __restrict__ outT, int R, int C) {
  __shared__ ushort tile[64][68];
  const int e = blockIdx.z;
  const int c0 = blockIdx.x * 64, r0 = blockIdx.y * 64;
  const float* ip = in + (size_t)e * R * C;
  const int cq = threadIdx.x & 15, rr = threadIdx.x >> 4;
  #pragma unroll
  for (int p = 0; p < 4; p++) {
    const int r = rr + 16 * p;
    float4 v = *reinterpret_cast<const float4*>(ip + (size_t)(r0 + r) * C + c0 + 4 * cq);
    ushort4 u = make_ushort4(f2bf(v.x), f2bf(v.y), f2bf(v.z), f2bf(v.w));
    *reinterpret_cast<ushort4*>(&tile[r][4 * cq]) = u;
  }
  __syncthreads();
  ushort* op = outT + (size_t)e * C * R;
  const int rq = threadIdx.x & 15, cc = threadIdx.x >> 4;
  #pragma unroll
  for (int p = 0; p < 4; p++) {
    const int c = cc + 16 * p;
    ushort4 u = make_ushort4(tile[4 * rq + 0][c], tile[4 * rq + 1][c],
                             tile[4 * rq + 2][c], tile[4 * rq + 3][c]);
    *reinterpret_cast<ushort4*>(op + (size_t)(c0 + c) * R + r0 + 4 * rq) = u;
  }
}

// ---------------- interleaving 64x64 transpose for W1a/W1b -> BT1 [E][4096][D]
__global__ __launch_bounds__(256) void k_transpose_pair64(const float* __restrict__ in,
                                                          ushort* __restrict__ outT, int half) {
  __shared__ ushort tile[64][68];
  const int e = blockIdx.z;
  const int f0 = blockIdx.x * 64, d0 = blockIdx.y * 64;
  const float* ip = in + (size_t)e * DD * FF;
  const int cq = threadIdx.x & 15, rr = threadIdx.x >> 4;
  #pragma unroll
  for (int p = 0; p < 4; p++) {
    const int r = rr + 16 * p;
    float4 v = *reinterpret_cast<const float4*>(ip + (size_t)(d0 + r) * FF + f0 + 4 * cq);
    ushort4 u = make_ushort4(f2bf(v.x), f2bf(v.y), f2bf(v.z), f2bf(v.w));
    *reinterpret_cast<ushort4*>(&tile[r][4 * cq]) = u;
  }
  __syncthreads();
  ushort* op = outT + (size_t)e * 4096 * DD;
  const int rq = threadIdx.x & 15, cc = threadIdx.x >> 4;
  #pragma unroll
  for (int p = 0; p < 4; p++) {
    const int f = f0 + cc + 16 * p;
    const int rmap = ((f >> 4) << 5) + half * 16 + (f & 15);
    ushort4 u = make_ushort4(tile[4 * rq + 0][cc + 16 * p], tile[4 * rq + 1][cc + 16 * p],
                             tile[4 * rq + 2][cc + 16 * p], tile[4 * rq + 3][cc + 16 * p]);
    *reinterpret_cast<ushort4*>(op + (size_t)rmap * DD + d0 + 4 * rq) = u;
  }
}

// ---------------- RMSNorm + gating (one block per token) ----------------
__global__ __launch_bounds__(256) void k_rms_gate(
    const float* __restrict__ x, const float* __restrict__ rms_w,
    const float* __restrict__ Wg, const float* __restrict__ bg,
    ushort* __restrict__ xn, float* __restrict__ outW,
    int* __restrict__ tk_e, float* __restrict__ tk_w, int* __restrict__ counts) {
  const int t = blockIdx.x, tid = threadIdx.x;
  const int wid = tid >> 6, lane = tid & 63;
  const float4 xv = reinterpret_cast<const float4*>(x + (size_t)t * DD)[tid];
  float ss = xv.x * xv.x + xv.y * xv.y + xv.z * xv.z + xv.w * xv.w;
  #pragma unroll
  for (int m = 32; m; m >>= 1) ss += __shfl_xor(ss, m);
  __shared__ float sred[4];
  __shared__ float slog[4][8];
  if (lane == 0) sred[wid] = ss;
  __syncthreads();
  const float ms = (sred[0] + sred[1] + sred[2] + sred[3]) * (1.0f / (float)DD);
  const float sc = 1.0f / sqrtf(ms + 1.1920929e-07f);   // finfo(f32).eps
  const float4 wv = reinterpret_cast<const float4*>(rms_w)[tid];
  float xs[4] = { xv.x * sc * wv.x, xv.y * sc * wv.y, xv.z * sc * wv.z, xv.w * sc * wv.w };
  ushort4 st = make_ushort4(f2bf(xs[0]), f2bf(xs[1]), f2bf(xs[2]), f2bf(xs[3]));
  reinterpret_cast<ushort4*>(xn + (size_t)t * DD)[tid] = st;
  float lg[8] = {0.f, 0.f, 0.f, 0.f, 0.f, 0.f, 0.f, 0.f};
  const float4* Wg4 = reinterpret_cast<const float4*>(Wg);
  const int d = tid * 4;
  #pragma unroll
  for (int j = 0; j < 4; j++) {
    float4 wa = Wg4[(d + j) * 2];
    float4 wb = Wg4[(d + j) * 2 + 1];
    lg[0] += xs[j] * wa.x; lg[1] += xs[j] * wa.y; lg[2] += xs[j] * wa.z; lg[3] += xs[j] * wa.w;
    lg[4] += xs[j] * wb.x; lg[5] += xs[j] * wb.y; lg[6] += xs[j] * wb.z; lg[7] += xs[j] * wb.w;
  }
  #pragma unroll
  for (int m = 32; m; m >>= 1) {
    #pragma unroll
    for (int i = 0; i < 8; i++) lg[i] += __shfl_xor(lg[i], m);
  }
  if (lane == 0) {
    #pragma unroll
    for (int i = 0; i < 8; i++) slog[wid][i] = lg[i];
  }
  __syncthreads();
  if (tid == 0) {
    float l[8];
    for (int i = 0; i < 8; i++)
      l[i] = slog[0][i] + slog[1][i] + slog[2][i] + slog[3][i] + bg[i];
    int i0 = 0; float v0 = l[0];
    for (int i = 1; i < 8; i++) if (l[i] > v0) { v0 = l[i]; i0 = i; }   // first max (jax tie rule)
    int i1 = -1; float v1 = -3.4e38f;
    for (int i = 0; i < 8; i++) if (i != i0 && l[i] > v1) { v1 = l[i]; i1 = i; }
    const float e1v = __expf(v1 - v0);
    const float w0 = 1.0f / (1.0f + e1v);
    const float w1 = e1v * w0;
    float* wrow = outW + (size_t)t * EE;
    for (int i = 0; i < 8; i++) wrow[i] = 0.f;
    wrow[i0] = w0; wrow[i1] = w1;
    tk_e[t] = i0 | (i1 << 8);
    tk_w[2 * t] = w0; tk_w[2 * t + 1] = w1;
    atomicAdd(&counts[i0], 1);
    atomicAdd(&counts[i1], 1);
  }
}

// ---------------- scan counts -> 256-aligned bases; init row map ----------------
__global__ void k_scan(const int* __restrict__ counts, int* __restrict__ base,
                       int* __restrict__ cursors, int* __restrict__ tok_of_row) {
  if (threadIdx.x == 0) {
    int acc = 0;
    for (int e = 0; e < EE; e++) {
      base[e] = acc;
      cursors[e] = 0;
      acc += ((counts[e] + 255) >> 8) << 8;
    }
    base[EE] = acc;
  }
  for (int i = threadIdx.x; i < NRCAP; i += 256) tok_of_row[i] = -1;
}

// ---------------- scatter tokens into expert-grouped rows ----------------
__global__ __launch_bounds__(256) void k_scatter(
    const int* __restrict__ tk_e, const int* __restrict__ base, int* __restrict__ cursors,
    int* __restrict__ tok_of_row, int* __restrict__ rows_of_tok) {
  const int t = blockIdx.x * 256 + threadIdx.x;
  if (t >= NT) return;
  const int ee = tk_e[t];
  const int e0 = ee & 255, e1 = (ee >> 8) & 255;
  int s = atomicAdd(&cursors[e0], 1);
  int row = base[e0] + s;
  tok_of_row[row] = t; rows_of_tok[2 * t] = row;
  s = atomicAdd(&cursors[e1], 1);
  row = base[e1] + s;
  tok_of_row[row] = t; rows_of_tok[2 * t + 1] = row;
}

// ---------------- grouped GEMM1: 256x256 tile, BK=64, 8 waves, m201-style 4-phase ----------------
// LDS: [2 dbuf][2 K-half] x {A[256][32], B[256][32]} bf16 = 128 KiB.
// Per phase (kh,mh): {ds_read frags (B held across mh pair); stage 1 half-step (2 gload_lds);
//   sched_barrier; s_barrier; setprio(1); 16 MFMA; setprio(0); [vmcnt(4) at ph1/ph3]; s_barrier}.
// In-flight invariant: exactly 8 loads outstanding at each vmcnt(4); the 4 drained are
// always the K-half needed next; the 4 newest ride across barriers (T4 counted vmcnt).
__global__ __launch_bounds__(512, 2) void k_ffn1(
    const ushort* __restrict__ xn, const ushort* __restrict__ BT1,
    const float* __restrict__ b1a, const float* __restrict__ b1b,
    const int* __restrict__ tok_of_row, const int* __restrict__ base,
    ushort* __restrict__ H) {
  const int row0 = blockIdx.y * 256;
  if (row0 >= base[EE]) return;
  int e = 0;
  while (e < EE - 1 && row0 >= base[e + 1]) e++;
  const int c0 = blockIdx.x * 256;            // interleaved column base
  const int tid = threadIdx.x;                // 0..511
  const int wid = tid >> 6, lane = tid & 63;
  const int wr = wid >> 2, wcn = wid & 3;     // 2 M-waves x 4 N-waves; wave out = 128x64
  __shared__ ushort sA[2][2][256 * 32];       // [dbuf][kh] 16 KiB each -> 64 KiB
  __shared__ ushort sB[2][2][256 * 32];       // 64 KiB

  // ---- staging map: issue i covers tile rows i*128..+127; thread -> (row, 16B chunk of 4)
  const int rT = tid >> 2;                    // 0..127
  const int cT = tid & 3;
  const int R0 = rT, R1 = 128 + rT;
  int tok0 = tok_of_row[row0 + R0]; if (tok0 < 0) tok0 = 0;
  int tok1 = tok_of_row[row0 + R1]; if (tok1 < 0) tok1 = 0;
  const int cg0 = cT ^ ((R0 >> 1) & 3);       // pre-swizzled global chunk
  const int cg1 = cT ^ ((R1 >> 1) & 3);
  const ushort* aSrc0 = xn + (size_t)tok0 * DD + cg0 * 8;
  const ushort* aSrc1 = xn + (size_t)tok1 * DD + cg1 * 8;
  const ushort* bSrc0 = BT1 + ((size_t)e * 4096 + c0 + R0) * DD + cg0 * 8;
  const ushort* bSrc1 = BT1 + ((size_t)e * 4096 + c0 + R1) * DD + cg1 * 8;
  const size_t ldso = (size_t)tid * 8;        // ushort idx; per-wave uniform base + lane*16B

  const int lrow = lane & 15, q = lane >> 4;

  f32x4 acc[8][4];
  #pragma unroll
  for (int m = 0; m < 8; m++)
    #pragma unroll
    for (int n = 0; n < 4; n++) acc[m][n] = (f32x4){0.f, 0.f, 0.f, 0.f};

  // prologue: stage tile 0's 4 half-steps into buf 0 (8 loads)
  #pragma unroll
  for (int s = 0; s < 4; s++) {
    const int kgl = (s >> 1) * 32;
    if (!(s & 1)) {
      gload16(aSrc0 + kgl, &sA[0][s >> 1][ldso]);
      gload16(aSrc1 + kgl, &sA[0][s >> 1][4096 + ldso]);
    } else {
      gload16(bSrc0 + kgl, &sB[0][s >> 1][ldso]);
      gload16(bSrc1 + kgl, &sB[0][s >> 1][4096 + ldso]);
    }
  }
  asm volatile("s_waitcnt vmcnt(4)" ::: "memory");   // K-half0 (oldest 4) landed
  __builtin_amdgcn_s_barrier();

  const int NKT = DD / 64;                    // 16 K-tiles
  for (int T = 0; T < NKT; T++) {
    const int cur = T & 1, nxt = cur ^ 1;
    const int koffN = ((T + 1) & (NKT - 1)) * 64;   // wrap: last prefetch redundant, keeps vmcnt uniform
    bf16x8 bf[4];
    #pragma unroll
    for (int ph = 0; ph < 4; ph++) {
      const int kh = ph >> 1, mh = ph & 1;
      const char* hA = reinterpret_cast<const char*>(&sA[cur][kh][0]);
      const char* hB = reinterpret_cast<const char*>(&sB[cur][kh][0]);
      if (mh == 0) {
        #pragma unroll
        for (int ni = 0; ni < 4; ni++) {
          const int brow = wcn * 64 + ni * 16 + lrow;
          bf[ni] = *reinterpret_cast<const bf16x8*>(hB + brow * 64 + ((q * 16) ^ swz_of_row(brow)));
        }
      }
      bf16x8 af[4];
      #pragma unroll
      for (int mi = 0; mi < 4; mi++) {
        const int arow = wr * 128 + (mh * 4 + mi) * 16 + lrow;
        af[mi] = *reinterpret_cast<const bf16x8*>(hA + arow * 64 + ((q * 16) ^ swz_of_row(arow)));
      }
      // stage half-step ph of tile T+1 (2 loads)
      {
        const int kgl = koffN + kh * 32;
        if (!(ph & 1)) {
          gload16(aSrc0 + kgl, &sA[nxt][kh][ldso]);
          gload16(aSrc1 + kgl, &sA[nxt][kh][4096 + ldso]);
        } else {
          gload16(bSrc0 + kgl, &sB[nxt][kh][ldso]);
          gload16(bSrc1 + kgl, &sB[nxt][kh][4096 + ldso]);
        }
      }
      __builtin_amdgcn_sched_barrier(0);   // pin reads+stage before the barrier
      __builtin_amdgcn_s_barrier();
      __builtin_amdgcn_s_setprio(1);
      #pragma unroll
      for (int mi = 0; mi < 4; mi++)
        #pragma unroll
        for (int ni = 0; ni < 4; ni++)
          acc[mh * 4 + mi][ni] =
              __builtin_amdgcn_mfma_f32_16x16x32_bf16(af[mi], bf[ni], acc[mh * 4 + mi][ni], 0, 0, 0);
      __builtin_amdgcn_s_setprio(0);
      if (mh == 1)   // end of ph1: publish next K-half1; end of ph3: publish tile T+1's K-half0
        asm volatile("s_waitcnt vmcnt(4)" ::: "memory");
      __builtin_amdgcn_s_barrier();
    }
  }

  // epilogue: pair interleaved cols (n even = a, n odd = b of same f-group)
  #pragma unroll
  for (int np = 0; np < 2; np++) {
    const int f = (c0 >> 1) + wcn * 32 + np * 16 + lrow;
    const float ba_ = b1a[e * FF + f], bb_ = b1b[e * FF + f];
    #pragma unroll
    for (int m = 0; m < 8; m++) {
      #pragma unroll
      for (int r = 0; r < 4; r++) {
        const float a = acc[m][2 * np][r] + ba_;
        const float b = acc[m][2 * np + 1][r] + bb_;
        const float h = (a / (1.0f + __expf(-a))) * b;
        const int grow = row0 + wr * 128 + m * 16 + q * 4 + r;
        H[(size_t)grow * FF + f] = f2bf(h);
      }
    }
  }
}

// ---------------- grouped GEMM2 (m97 structure): Y[row] = H@W2 + b2 (dense stores) ----------------
__global__ __launch_bounds__(256) void k_ffn2(
    const ushort* __restrict__ H, const ushort* __restrict__ W2T, const float* __restrict__ b2,
    const int* __restrict__ base, float* __restrict__ Y) {
  const int row0 = blockIdx.y * 128;
  if (row0 >= base[EE]) return;
  int e = 0;
  while (e < EE - 1 && row0 >= base[e + 1]) e++;
  const int d0 = blockIdx.x * 128;
  const int tid = threadIdx.x, wid = tid >> 6, lane = tid & 63;
  const int wr = wid >> 1, wc = wid & 1;
  __shared__ ushort sA[128 * 32], sB[128 * 32];
  const int rloc = tid >> 2;
  const int kcol = (((tid & 3) * 16) ^ swz_of_row(rloc)) >> 1;
  const ushort* gA0 = H + (size_t)(row0 + rloc) * FF + kcol;
  const ushort* gA1 = H + (size_t)(row0 + 64 + rloc) * FF + kcol;
  const ushort* gB0 = W2T + ((size_t)e * DD + d0 + rloc) * FF + kcol;
  const ushort* gB1 = W2T + ((size_t)e * DD + d0 + 64 + rloc) * FF + kcol;
  ushort* lA0 = sA + wid * 512;  ushort* lA1 = sA + 2048 + wid * 512;
  ushort* lB0 = sB + wid * 512;  ushort* lB1 = sB + 2048 + wid * 512;
  const int lrow = lane & 15, q = lane >> 4;
  const int fsw = (q * 16) ^ swz_of_row(lrow);
  int aoff[4], boff[4];
  #pragma unroll
  for (int m = 0; m < 4; m++) aoff[m] = (wr * 64 + m * 16 + lrow) * 64 + fsw;
  #pragma unroll
  for (int n = 0; n < 4; n++) boff[n] = (wc * 64 + n * 16 + lrow) * 64 + fsw;
  f32x4 acc[16];
  #pragma unroll
  for (int i = 0; i < 16; i++) acc[i] = (f32x4){0.f, 0.f, 0.f, 0.f};
  for (int kt = 0; kt < FF / 32; kt++) {
    gload16(gA0 + kt * 32, lA0);
    gload16(gA1 + kt * 32, lA1);
    gload16(gB0 + kt * 32, lB0);
    gload16(gB1 + kt * 32, lB1);
    __syncthreads();
    bf16x8 fb[4];
    #pragma unroll
    for (int n = 0; n < 4; n++)
      fb[n] = *reinterpret_cast<const bf16x8*>(reinterpret_cast<const char*>(sB) + boff[n]);
    #pragma unroll
    for (int m = 0; m < 4; m++) {
      const bf16x8 fa = *reinterpret_cast<const bf16x8*>(reinterpret_cast<const char*>(sA) + aoff[m]);
      #pragma unroll
      for (int n = 0; n < 4; n++)
        acc[m * 4 + n] = __builtin_amdgcn_mfma_f32_16x16x32_bf16(fa, fb[n], acc[m * 4 + n], 0, 0, 0);
    }
    __syncthreads();
  }
  #pragma unroll
  for (int n = 0; n < 4; n++) {
    const int dcol = d0 + wc * 64 + n * 16 + lrow;
    const float bias = b2[e * DD + dcol];
    #pragma unroll
    for (int m = 0; m < 4; m++) {
      #pragma unroll
      for (int r = 0; r < 4; r++) {
        const int grow = row0 + wr * 64 + m * 16 + q * 4 + r;
        Y[(size_t)grow * DD + dcol] = acc[m * 4 + n][r] + bias;
      }
    }
  }
}

// ---------------- gather: out[t] = w0*Y[r0] + w1*Y[r1] ----------------
__global__ __launch_bounds__(256) void k_gather(
    const float* __restrict__ Y, const int* __restrict__ rows_of_tok,
    const float* __restrict__ tk_w, float* __restrict__ out0) {
  const int t = blockIdx.x;
  const int r0 = rows_of_tok[2 * t], r1 = rows_of_tok[2 * t + 1];
  const float w0 = tk_w[2 * t], w1 = tk_w[2 * t + 1];
  const float4 y0 = reinterpret_cast<const float4*>(Y + (size_t)r0 * DD)[threadIdx.x];
  const float4 y1 = reinterpret_cast<const float4*>(Y + (size_t)r1 * DD)[threadIdx.x];
  float4 o;
  o.x = w0 * y0.x + w1 * y1.x;
  o.y = w0 * y0.y + w1 * y1.y;
  o.z = w0 * y0.z + w1 * y1.z;
  o.w = w0 * y0.w + w1 * y1.w;
  reinterpret_cast<float4*>(out0 + (size_t)t * DD)[threadIdx.x] = o;
}

// ---------------- workspace layout (bytes); total ~193.2 MB ----------------
// Y (fp32 [NRCAP*DD] = 75,497,472) aliases XN+BT1 (83.9 MB, dead by ffn2 time).
#define WS_Y    ((size_t)0)
#define WS_XN   ((size_t)0)                    // bf16 [NT*DD]          16,777,216
#define WS_BT1  ((size_t)16777216)             // bf16 [EE*4096*DD]     67,108,864
#define WS_W2T  ((size_t)83886080)             // bf16 [EE*DD*FF]       33,554,432
#define WS_H    ((size_t)117440512)            // bf16 [NRCAP*FF]       75,497,472
#define WS_TOK  ((size_t)192937984)            // int  [NRCAP]
#define WS_ROWS ((size_t)193011712)            // int  [2*NT]
#define WS_TKE  ((size_t)193077248)            // int  [NT]
#define WS_TKW  ((size_t)193110016)            // f32  [2*NT]
#define WS_CNT  ((size_t)193175552)            // int  [8]
#define WS_BASE ((size_t)193175616)            // int  [9]
#define WS_CUR  ((size_t)193175680)            // int  [8]

extern "C" void kernel_launch(void* const* d_in, const int* in_sizes, int n_in,
                              void* d_out, int out_size, void* d_ws, size_t ws_size,
                              hipStream_t stream) {
  const float* x     = (const float*)d_in[0];
  const float* rms_w = (const float*)d_in[1];
  const float* Wg    = (const float*)d_in[2];
  const float* bg    = (const float*)d_in[3];
  const float* W1a   = (const float*)d_in[4];
  const float* b1a   = (const float*)d_in[5];
  const float* W1b   = (const float*)d_in[6];
  const float* b1b   = (const float*)d_in[7];
  const float* W2    = (const float*)d_in[8];
  const float* b2    = (const float*)d_in[9];
  float* out0 = (float*)d_out;                       // [NT*DD]
  float* outW = (float*)d_out + (size_t)NT * DD;     // [NT*EE]

  char* ws = (char*)d_ws;
  ushort* xn    = (ushort*)(ws + WS_XN);
  ushort* BT1   = (ushort*)(ws + WS_BT1);
  ushort* W2T   = (ushort*)(ws + WS_W2T);
  ushort* Hbuf  = (ushort*)(ws + WS_H);
  float*  Ybuf  = (float*)(ws + WS_Y);
  int*    tok   = (int*)(ws + WS_TOK);
  int*    rows  = (int*)(ws + WS_ROWS);
  int*    tk_e  = (int*)(ws + WS_TKE);
  float*  tk_w  = (float*)(ws + WS_TKW);
  int*    cnt   = (int*)(ws + WS_CNT);
  int*    base  = (int*)(ws + WS_BASE);
  int*    cur   = (int*)(ws + WS_CUR);

  hipMemsetAsync(cnt, 0, 8 * sizeof(int), stream);

  // weight transpose+cast (every launch; weights are inputs)
  k_transpose_pair64<<<dim3(FF / 64, DD / 64, EE), 256, 0, stream>>>(W1a, BT1, 0);
  k_transpose_pair64<<<dim3(FF / 64, DD / 64, EE), 256, 0, stream>>>(W1b, BT1, 1);
  k_transpose64<<<dim3(DD / 64, FF / 64, EE), 256, 0, stream>>>(W2, W2T, FF, DD);

  k_rms_gate<<<NT, 256, 0, stream>>>(x, rms_w, Wg, bg, xn, outW, tk_e, tk_w, cnt);
  k_scan<<<1, 256, 0, stream>>>(cnt, base, cur, tok);
  k_scatter<<<NT / 256, 256, 0, stream>>>(tk_e, base, cur, tok, rows);

  k_ffn1<<<dim3(4096 / 256, MAXT256), 512, 0, stream>>>(xn, BT1, b1a, b1b, tok, base, Hbuf);
  k_ffn2<<<dim3(DD / 128, MAXT128), 256, 0, stream>>>(Hbuf, W2T, b2, base, Ybuf);
  k_gather<<<NT, 256, 0, stream>>>(Ybuf, rows, tk_w, out0);
}